// Round 10
// baseline (319.839 us; speedup 1.0000x reference)
//
#include <hip/hip_runtime.h>

#define P_N 2048
#define Q_N 512
#define A_N 48
#define CHUNK 256
#define CAP 32
#define LSTR 33   // list stride: bank = (tid*33 + k) % 32 varies with tid, conflict-free

// plain numpy-f32 3-term dot: ((x*x' + y*y') + z*z'), each op separately rounded
__device__ __forceinline__ float dot3_rn(float ax, float ay, float az,
                                         float bx, float by, float bz) {
    return __fadd_rn(__fadd_rn(__fmul_rn(ax, bx), __fmul_rn(ay, by)),
                     __fmul_rn(az, bz));
}

// XLA fused mul+reduce FMA chain: fma(z,z', fma(y,y', rn(x*x')))
__device__ __forceinline__ float dot3_fma(float ax, float ay, float az,
                                          float bx, float by, float bz) {
    return __fmaf_rn(az, bz, __fmaf_rn(ay, by, __fmul_rn(ax, bx)));
}

// sorted insert (ascending) into 16-entry register list; stable for equal keys
__device__ __forceinline__ void insert16(float d, int idx, float (&td)[16], int (&ti)[16]) {
    if (d >= td[15]) return;
    #pragma unroll
    for (int j = 15; j >= 1; --j) {
        float oldd = td[j]; int oldi = ti[j];
        bool up   = (d < td[j - 1]);
        bool here = (d < oldd);
        td[j] = up ? td[j - 1] : (here ? d : oldd);
        ti[j] = up ? ti[j - 1] : (here ? idx : oldi);
    }
    if (d < td[0]) { ti[0] = idx; td[0] = d; }
}

__global__ __launch_bounds__(64, 4) void aronet_kernel(
        const float* __restrict__ pcd, const float* __restrict__ qry,
        const float* __restrict__ anc, float* __restrict__ out) {
    __shared__ float4 spt[P_N];            // (dist, dirx, diry, dirz) per point: 32 KiB
    __shared__ float  sdist[64 * LSTR];    // per-thread candidate dists
    __shared__ int    sidx [64 * LSTR];    // per-thread candidate indices

    const int tid = threadIdx.x;
    const int bid = blockIdx.x;            // (b*48 + a)*8 + qc
    const int qc  = bid & 7;
    const int ba  = bid >> 3;              // 0..95
    const int a   = ba % A_N;
    const int b   = ba / A_N;

    const float ax = anc[(b * A_N + a) * 3 + 0];
    const float ay = anc[(b * A_N + a) * 3 + 1];
    const float az = anc[(b * A_N + a) * 3 + 2];

    // ---- stage anchor->point dist/dir in LDS ----
    // XLA rsqrt-rewrite-on-CPU profile: dir = vec * rn(1 / rn(sqrt(d2)))
    const float* pbase = pcd + (size_t)b * P_N * 3;
    for (int p = tid; p < P_N; p += 64) {
        float vx = __fsub_rn(pbase[p * 3 + 0], ax);
        float vy = __fsub_rn(pbase[p * 3 + 1], ay);
        float vz = __fsub_rn(pbase[p * 3 + 2], az);
        float d2 = dot3_rn(vx, vy, vz, vx, vy, vz);
        float dist = __fsqrt_rn(d2);
        float r = __fdiv_rn(1.0f, dist);        // correctly-rounded reciprocal
        float dx = __fmul_rn(vx, r);
        float dy = __fmul_rn(vy, r);
        float dz = __fmul_rn(vz, r);
        spt[p] = make_float4(dist, dx, dy, dz);
    }
    __syncthreads();

    // ---- per-thread query setup (same reciprocal-multiply normalization) ----
    const int q = (qc << 6) + tid;         // 0..511
    const float qx = qry[((size_t)b * Q_N + q) * 3 + 0];
    const float qy = qry[((size_t)b * Q_N + q) * 3 + 1];
    const float qz = qry[((size_t)b * Q_N + q) * 3 + 2];
    const float vqx = __fsub_rn(qx, ax);
    const float vqy = __fsub_rn(qy, ay);
    const float vqz = __fsub_rn(qz, az);
    const float qd2 = dot3_rn(vqx, vqy, vqz, vqx, vqy, vqz);
    const float qdist = __fsqrt_rn(qd2);
    const float qr = __fdiv_rn(1.0f, qdist);
    const float dqx = __fmul_rn(vqx, qr);
    const float dqy = __fmul_rn(vqy, qr);
    const float dqz = __fmul_rn(vqz, qr);

    const float COS_TH = 0.9659258262890683f;  // f32 demotion of python float threshold

    float td[16]; int ti[16];
    #pragma unroll
    for (int j = 0; j < 16; ++j) { td[j] = __builtin_inff(); ti[j] = 0; }

    // ---- scan points in chunks: compact candidates to LDS, then merge ----
    const int lbase = tid * LSTR;
    int cnt = 0;
    for (int p0 = 0; p0 < P_N; p0 += CHUNK) {
        #pragma unroll 4
        for (int p = p0; p < p0 + CHUNK; ++p) {
            float4 pt = spt[p];   // wave-uniform broadcast read, conflict-free
            float cosv = dot3_fma(dqx, dqy, dqz, pt.y, pt.z, pt.w);
            // reference: masked = where(cos <= TH, inf, dist); candidate iff !(cos <= TH)
            if (!(cosv <= COS_TH)) {
                if (cnt < CAP) {
                    sdist[lbase + cnt] = pt.x;
                    sidx [lbase + cnt] = p;
                    cnt++;
                } else {
                    insert16(pt.x, p, td, ti);   // overflow fallback (rare)
                }
            }
        }
        for (int k = 0; k < cnt; ++k) {
            insert16(sdist[lbase + k], sidx[lbase + k], td, ti);
        }
        cnt = 0;
    }

    // ---- emit features: out[b][q][a][0..16][0..3] as float32 ----
    float4* o = (float4*)(out + (((size_t)(b * Q_N + q) * A_N + a) * 17) * 4);

    o[0] = make_float4(vqx, vqy, vqz, qdist);

    #pragma unroll
    for (int j = 0; j < 16; ++j) {
        float4 w;
        if (td[j] == __builtin_inff()) {
            w = make_float4(0.0f, 0.0f, 0.0f, 0.0f);   // padded slot -> exact zeros
        } else {
            const float* hp = pbase + (size_t)ti[j] * 3;
            float hx = __fsub_rn(hp[0], qx);
            float hy = __fsub_rn(hp[1], qy);
            float hz = __fsub_rn(hp[2], qz);
            float sq = dot3_rn(hx, hy, hz, hx, hy, hz);
            float md = (sq == 0.0f) ? 0.0f : __fsqrt_rn(sq);
            w = make_float4(hx, hy, hz, md);
        }
        o[1 + j] = w;
    }
}

extern "C" void kernel_launch(void* const* d_in, const int* in_sizes, int n_in,
                              void* d_out, int out_size, void* d_ws, size_t ws_size,
                              hipStream_t stream) {
    const float* pcd = (const float*)d_in[0];
    const float* qry = (const float*)d_in[1];
    const float* anc = (const float*)d_in[2];
    float* out = (float*)d_out;

    dim3 grid(2 * A_N * 8);   // b * anchors * query-chunks = 768 blocks
    dim3 block(64);
    hipLaunchKernelGGL(aronet_kernel, grid, block, 0, stream, pcd, qry, anc, out);
}

// Round 11
// 192.801 us; speedup vs baseline: 1.6589x; 1.6589x over previous
//
#include <hip/hip_runtime.h>

#define P_N 2048
#define Q_N 512
#define A_N 48
#define NW 4                 // waves per block
#define WPTS (P_N / NW)      // 512 points scanned per wave
#define CHUNK 256
#define CAP 32

// plain numpy-f32 3-term dot: ((x*x' + y*y') + z*z'), each op separately rounded
__device__ __forceinline__ float dot3_rn(float ax, float ay, float az,
                                         float bx, float by, float bz) {
    return __fadd_rn(__fadd_rn(__fmul_rn(ax, bx), __fmul_rn(ay, by)),
                     __fmul_rn(az, bz));
}

// XLA fused mul+reduce FMA chain: fma(z,z', fma(y,y', rn(x*x')))
__device__ __forceinline__ float dot3_fma(float ax, float ay, float az,
                                          float bx, float by, float bz) {
    return __fmaf_rn(az, bz, __fmaf_rn(ay, by, __fmul_rn(ax, bx)));
}

// sorted insert (ascending) into 16-entry register list; stable for equal keys
__device__ __forceinline__ void insert16(float d, int idx, float (&td)[16], int (&ti)[16]) {
    if (d >= td[15]) return;
    #pragma unroll
    for (int j = 15; j >= 1; --j) {
        float oldd = td[j]; int oldi = ti[j];
        bool up   = (d < td[j - 1]);
        bool here = (d < oldd);
        td[j] = up ? td[j - 1] : (here ? d : oldd);
        ti[j] = up ? ti[j - 1] : (here ? idx : oldi);
    }
    if (d < td[0]) { ti[0] = idx; td[0] = d; }
}

__global__ __launch_bounds__(256, 3) void aronet_kernel(
        const float* __restrict__ pcd, const float* __restrict__ qry,
        const float* __restrict__ anc, float* __restrict__ out) {
    __shared__ float4 spt[P_N];          // (dist, dirx, diry, dirz): 32 KiB
    __shared__ float  scratch_f[4896];   // 19584 B: cand(16896) ∪ merge(19584)

    // scan-phase view: per-thread candidate index lists [256][33] ushort
    unsigned short* cand = (unsigned short*)scratch_f;
    // merge-phase view (after scan barrier): partial top-16 of waves 1..3
    float*          mdist = scratch_f;                               // [3][64][17] f32
    unsigned short* midx  = (unsigned short*)(scratch_f + 3264);     // [3][64][17] u16

    const int tid  = threadIdx.x;
    const int lane = tid & 63;
    const int w    = tid >> 6;           // wave id 0..3

    const int bid = blockIdx.x;          // (b*48 + a)*8 + qc
    const int qc  = bid & 7;
    const int ba  = bid >> 3;            // 0..95
    const int a   = ba % A_N;
    const int b   = ba / A_N;

    const float ax = anc[(b * A_N + a) * 3 + 0];
    const float ay = anc[(b * A_N + a) * 3 + 1];
    const float az = anc[(b * A_N + a) * 3 + 2];

    // ---- each wave stages ITS OWN point-quarter (no cross-wave dependency) ----
    // profile (verified passing): d2 plain, dist = sqrt_rn(d2), dir = vec * rn(1/dist)
    const float* pbase = pcd + (size_t)b * P_N * 3;
    const int pq0 = w * WPTS;
    for (int i = lane; i < WPTS; i += 64) {
        const int p = pq0 + i;
        float vx = __fsub_rn(pbase[p * 3 + 0], ax);
        float vy = __fsub_rn(pbase[p * 3 + 1], ay);
        float vz = __fsub_rn(pbase[p * 3 + 2], az);
        float d2 = dot3_rn(vx, vy, vz, vx, vy, vz);
        float dist = __fsqrt_rn(d2);
        float r = __fdiv_rn(1.0f, dist);
        spt[p] = make_float4(dist, __fmul_rn(vx, r), __fmul_rn(vy, r), __fmul_rn(vz, r));
    }

    // ---- per-lane query setup (all waves compute the same 64 queries) ----
    const int q = (qc << 6) + lane;      // 0..511
    const float qx = qry[((size_t)b * Q_N + q) * 3 + 0];
    const float qy = qry[((size_t)b * Q_N + q) * 3 + 1];
    const float qz = qry[((size_t)b * Q_N + q) * 3 + 2];
    const float vqx = __fsub_rn(qx, ax);
    const float vqy = __fsub_rn(qy, ay);
    const float vqz = __fsub_rn(qz, az);
    const float qd2 = dot3_rn(vqx, vqy, vqz, vqx, vqy, vqz);
    const float qdist = __fsqrt_rn(qd2);
    const float qr = __fdiv_rn(1.0f, qdist);
    const float dqx = __fmul_rn(vqx, qr);
    const float dqy = __fmul_rn(vqy, qr);
    const float dqz = __fmul_rn(vqz, qr);

    const float COS_TH = 0.9659258262890683f;

    float td[16]; int ti[16];
    #pragma unroll
    for (int j = 0; j < 16; ++j) { td[j] = __builtin_inff(); ti[j] = 0; }

    // ---- scan own quarter in chunks: compact in-cone indices, then merge ----
    const int lbase = tid * 33;
    int cnt = 0;
    for (int c0 = pq0; c0 < pq0 + WPTS; c0 += CHUNK) {
        #pragma unroll 4
        for (int p = c0; p < c0 + CHUNK; ++p) {
            float4 pt = spt[p];          // wave-uniform broadcast read
            float cosv = dot3_fma(dqx, dqy, dqz, pt.y, pt.z, pt.w);
            if (!(cosv <= COS_TH)) {     // candidate iff !(cos <= TH)
                if (cnt < CAP) { cand[lbase + cnt] = (unsigned short)p; cnt++; }
                else insert16(pt.x, p, td, ti);   // overflow fallback (rare)
            }
        }
        for (int k = 0; k < cnt; ++k) {
            int i = cand[lbase + k];
            insert16(spt[i].x, i, td, ti);
        }
        cnt = 0;
    }

    // ---- cross-wave merge: waves 1..3 publish partials, wave 0 merges ----
    __syncthreads();                     // scans done; scratch becomes merge buffer
    if (w > 0) {
        const int mb = ((w - 1) * 64 + lane) * 17;   // stride 17: conflict-free
        #pragma unroll
        for (int k = 0; k < 16; ++k) {
            mdist[mb + k] = td[k];
            midx [mb + k] = (unsigned short)ti[k];
        }
    }
    __syncthreads();

    if (w == 0) {
        // ascending wave order == ascending index range -> stable-tie semantics
        for (int w2 = 0; w2 < NW - 1; ++w2) {
            const int mb = (w2 * 64 + lane) * 17;
            #pragma unroll
            for (int k = 0; k < 16; ++k) {
                float d = mdist[mb + k];
                if (d < __builtin_inff()) insert16(d, (int)midx[mb + k], td, ti);
            }
        }

        // ---- emit features: out[b][q][a][0..16][0..3] as float32 ----
        float4* o = (float4*)(out + (((size_t)(b * Q_N + q) * A_N + a) * 17) * 4);
        o[0] = make_float4(vqx, vqy, vqz, qdist);

        #pragma unroll
        for (int j = 0; j < 16; ++j) {
            float4 wv;
            if (td[j] == __builtin_inff()) {
                wv = make_float4(0.0f, 0.0f, 0.0f, 0.0f);   // padded -> exact zeros
            } else {
                const float* hp = pbase + (size_t)ti[j] * 3;
                float hx = __fsub_rn(hp[0], qx);
                float hy = __fsub_rn(hp[1], qy);
                float hz = __fsub_rn(hp[2], qz);
                float sq = dot3_rn(hx, hy, hz, hx, hy, hz);
                float md = (sq == 0.0f) ? 0.0f : __fsqrt_rn(sq);
                wv = make_float4(hx, hy, hz, md);
            }
            o[1 + j] = wv;
        }
    }
}

extern "C" void kernel_launch(void* const* d_in, const int* in_sizes, int n_in,
                              void* d_out, int out_size, void* d_ws, size_t ws_size,
                              hipStream_t stream) {
    const float* pcd = (const float*)d_in[0];
    const float* qry = (const float*)d_in[1];
    const float* anc = (const float*)d_in[2];
    float* out = (float*)d_out;

    dim3 grid(2 * A_N * 8);   // (b, anchor, 64-query chunk) = 768 blocks
    dim3 block(256);          // 4 waves: each scans a point-quarter
    hipLaunchKernelGGL(aronet_kernel, grid, block, 0, stream, pcd, qry, anc, out);
}